// Round 1
// baseline (3145.711 us; speedup 1.0000x reference)
//
#include <hip/hip_runtime.h>

#define N_NODES 100000
#define N_EDGES 1600000
#define IN_F 256
#define OUT_F 128

// h[n][c] = (sum_k feat[n][k] * W[k][c]) * cj[n]
// block = 256 threads = 8 nodes x 32 threads; each thread computes 4 consecutive cols.
__global__ __launch_bounds__(256) void gemm_cj_kernel(const float* __restrict__ feat,
                                                      const float* __restrict__ W,
                                                      const float* __restrict__ cj,
                                                      float* __restrict__ h) {
    int node = blockIdx.x * 8 + (threadIdx.x >> 5);
    int c4 = (threadIdx.x & 31) * 4;
    if (node >= N_NODES) return;

    const float4* f4 = reinterpret_cast<const float4*>(feat + (size_t)node * IN_F);
    float4 acc = make_float4(0.f, 0.f, 0.f, 0.f);

    #pragma unroll 4
    for (int k = 0; k < IN_F; k += 4) {
        float4 f = f4[k >> 2];
        const float* wp = W + (size_t)k * OUT_F + c4;
        float4 w0 = *reinterpret_cast<const float4*>(wp);
        float4 w1 = *reinterpret_cast<const float4*>(wp + OUT_F);
        float4 w2 = *reinterpret_cast<const float4*>(wp + 2 * OUT_F);
        float4 w3 = *reinterpret_cast<const float4*>(wp + 3 * OUT_F);
        acc.x = fmaf(f.x, w0.x, acc.x); acc.y = fmaf(f.x, w0.y, acc.y);
        acc.z = fmaf(f.x, w0.z, acc.z); acc.w = fmaf(f.x, w0.w, acc.w);
        acc.x = fmaf(f.y, w1.x, acc.x); acc.y = fmaf(f.y, w1.y, acc.y);
        acc.z = fmaf(f.y, w1.z, acc.z); acc.w = fmaf(f.y, w1.w, acc.w);
        acc.x = fmaf(f.z, w2.x, acc.x); acc.y = fmaf(f.z, w2.y, acc.y);
        acc.z = fmaf(f.z, w2.z, acc.z); acc.w = fmaf(f.z, w2.w, acc.w);
        acc.x = fmaf(f.w, w3.x, acc.x); acc.y = fmaf(f.w, w3.y, acc.y);
        acc.z = fmaf(f.w, w3.z, acc.z); acc.w = fmaf(f.w, w3.w, acc.w);
    }

    float s = cj[node];
    acc.x *= s; acc.y *= s; acc.z *= s; acc.w *= s;
    *reinterpret_cast<float4*>(h + (size_t)node * OUT_F + c4) = acc;
}

// One edge per 32-lane group; each lane handles 4 consecutive cols.
// msg = h[src] * ci[dst], atomically accumulated into out[dst].
__global__ __launch_bounds__(256) void scatter_kernel(const float* __restrict__ h,
                                                      const float* __restrict__ ci,
                                                      const int* __restrict__ src,
                                                      const int* __restrict__ dst,
                                                      float* __restrict__ out) {
    int gid = blockIdx.x * blockDim.x + threadIdx.x;
    int e = gid >> 5;
    if (e >= N_EDGES) return;
    int lane = gid & 31;

    int s = src[e];
    int d = dst[e];
    float scale = ci[d];

    float4 m = *reinterpret_cast<const float4*>(h + (size_t)s * OUT_F + lane * 4);
    float* o = out + (size_t)d * OUT_F + lane * 4;
    atomicAdd(o + 0, m.x * scale);
    atomicAdd(o + 1, m.y * scale);
    atomicAdd(o + 2, m.z * scale);
    atomicAdd(o + 3, m.w * scale);
}

extern "C" void kernel_launch(void* const* d_in, const int* in_sizes, int n_in,
                              void* d_out, int out_size, void* d_ws, size_t ws_size,
                              hipStream_t stream) {
    const float* feat = (const float*)d_in[0];
    const float* W    = (const float*)d_in[1];
    const float* cj   = (const float*)d_in[2];
    const float* ci   = (const float*)d_in[3];
    const int*   src  = (const int*)d_in[4];
    const int*   dst  = (const int*)d_in[5];
    float* out = (float*)d_out;
    float* h   = (float*)d_ws;   // N_NODES * OUT_F fp32 = 51.2 MB

    // Output accumulates via atomics -> must start from zero every call.
    hipMemsetAsync(d_out, 0, (size_t)out_size * sizeof(float), stream);

    gemm_cj_kernel<<<(N_NODES + 7) / 8, 256, 0, stream>>>(feat, W, cj, h);

    // 32 lanes per edge -> N_EDGES*32 threads total.
    int scatter_blocks = (int)(((long long)N_EDGES * 32 + 255) / 256);
    scatter_kernel<<<scatter_blocks, 256, 0, stream>>>(h, ci, src, dst, out);
}

// Round 2
// 734.296 us; speedup vs baseline: 4.2840x; 4.2840x over previous
//
#include <hip/hip_runtime.h>

#define N_NODES 100000
#define N_EDGES 1600000
#define IN_F 256
#define OUT_F 128

// ---------------- GEMM: h[n][c] = (feat[n,:] @ W[:,c]) * cj[n] ----------------
// block = 256 = 8 groups of 32 lanes; each group computes 4 nodes x 128 cols.
// Each lane: 4 nodes x 4 consecutive cols. W float4 loads reused across 4 nodes.
__device__ __forceinline__ void fma4(float4& a, float s, const float4& w) {
    a.x = fmaf(s, w.x, a.x); a.y = fmaf(s, w.y, a.y);
    a.z = fmaf(s, w.z, a.z); a.w = fmaf(s, w.w, a.w);
}

__global__ __launch_bounds__(256) void gemm_cj_kernel(const float* __restrict__ feat,
                                                      const float* __restrict__ W,
                                                      const float* __restrict__ cj,
                                                      float* __restrict__ h) {
    int g    = threadIdx.x >> 5;
    int lane = threadIdx.x & 31;
    int n0   = blockIdx.x * 32 + g * 4;       // this group's 4 nodes
    int c4   = lane * 4;                      // this lane's 4 cols

    const float4* W4 = reinterpret_cast<const float4*>(W);
    const float4* f0 = reinterpret_cast<const float4*>(feat + (size_t)(n0 + 0) * IN_F);
    const float4* f1 = reinterpret_cast<const float4*>(feat + (size_t)(n0 + 1) * IN_F);
    const float4* f2 = reinterpret_cast<const float4*>(feat + (size_t)(n0 + 2) * IN_F);
    const float4* f3 = reinterpret_cast<const float4*>(feat + (size_t)(n0 + 3) * IN_F);

    float4 a0 = make_float4(0,0,0,0), a1 = a0, a2 = a0, a3 = a0;

    #pragma unroll 2
    for (int k = 0; k < IN_F; k += 4) {
        float4 x0 = f0[k >> 2];
        float4 x1 = f1[k >> 2];
        float4 x2 = f2[k >> 2];
        float4 x3 = f3[k >> 2];
        float4 w0 = W4[((k + 0) * OUT_F + c4) >> 2];
        float4 w1 = W4[((k + 1) * OUT_F + c4) >> 2];
        float4 w2 = W4[((k + 2) * OUT_F + c4) >> 2];
        float4 w3 = W4[((k + 3) * OUT_F + c4) >> 2];

        fma4(a0, x0.x, w0); fma4(a0, x0.y, w1); fma4(a0, x0.z, w2); fma4(a0, x0.w, w3);
        fma4(a1, x1.x, w0); fma4(a1, x1.y, w1); fma4(a1, x1.z, w2); fma4(a1, x1.w, w3);
        fma4(a2, x2.x, w0); fma4(a2, x2.y, w1); fma4(a2, x2.z, w2); fma4(a2, x2.w, w3);
        fma4(a3, x3.x, w0); fma4(a3, x3.y, w1); fma4(a3, x3.z, w2); fma4(a3, x3.w, w3);
    }

    float s0 = cj[n0 + 0], s1 = cj[n0 + 1], s2 = cj[n0 + 2], s3 = cj[n0 + 3];
    float4* h4 = reinterpret_cast<float4*>(h);
    a0.x *= s0; a0.y *= s0; a0.z *= s0; a0.w *= s0;
    a1.x *= s1; a1.y *= s1; a1.z *= s1; a1.w *= s1;
    a2.x *= s2; a2.y *= s2; a2.z *= s2; a2.w *= s2;
    a3.x *= s3; a3.y *= s3; a3.z *= s3; a3.w *= s3;
    h4[((size_t)(n0 + 0) * OUT_F + c4) >> 2] = a0;
    h4[((size_t)(n0 + 1) * OUT_F + c4) >> 2] = a1;
    h4[((size_t)(n0 + 2) * OUT_F + c4) >> 2] = a2;
    h4[((size_t)(n0 + 3) * OUT_F + c4) >> 2] = a3;
}

// ---------------- CSR build ----------------
__global__ __launch_bounds__(256) void count_kernel(const int* __restrict__ dst,
                                                    int* __restrict__ cursor) {
    int e = blockIdx.x * 256 + threadIdx.x;
    if (e < N_EDGES) atomicAdd(&cursor[dst[e]], 1);
}

// Single block of 1024 threads: exclusive scan of cursor(=counts) -> offsets,
// and reset cursor[i] to the segment start.
__global__ __launch_bounds__(1024) void scan_kernel(int* __restrict__ cursor,
                                                    int* __restrict__ offsets) {
    __shared__ int sdata[1024];
    const int t = threadIdx.x;
    const int CHUNK = (N_NODES + 1023) / 1024;   // 98
    int lo = t * CHUNK;
    int hi = min(lo + CHUNK, N_NODES);

    int sum = 0;
    for (int i = lo; i < hi; ++i) sum += cursor[i];
    sdata[t] = sum;
    __syncthreads();

    // Hillis-Steele inclusive scan
    for (int off = 1; off < 1024; off <<= 1) {
        int v = 0;
        if (t >= off) v = sdata[t - off];
        __syncthreads();
        sdata[t] += v;
        __syncthreads();
    }
    int run = sdata[t] - sum;   // exclusive prefix for this chunk

    for (int i = lo; i < hi; ++i) {
        int c = cursor[i];
        offsets[i] = run;
        cursor[i]  = run;       // becomes the fill cursor
        run += c;
    }
    if (t == 0) offsets[N_NODES] = N_EDGES;
}

__global__ __launch_bounds__(256) void fill_kernel(const int* __restrict__ src,
                                                   const int* __restrict__ dst,
                                                   int* __restrict__ cursor,
                                                   int* __restrict__ bin_src) {
    int e = blockIdx.x * 256 + threadIdx.x;
    if (e < N_EDGES) {
        int pos = atomicAdd(&cursor[dst[e]], 1);
        bin_src[pos] = src[e];
    }
}

// ---------------- Gather: out[d][c] = ci[d] * sum_{e in bin(d)} h[src_e][c] -----
// 32 lanes per node, float4 per lane -> one coalesced 512B row read per edge.
__global__ __launch_bounds__(256) void gather_kernel(const float* __restrict__ h,
                                                     const float* __restrict__ ci,
                                                     const int* __restrict__ offsets,
                                                     const int* __restrict__ bin_src,
                                                     float* __restrict__ out) {
    int node = blockIdx.x * 8 + (threadIdx.x >> 5);
    int lane = threadIdx.x & 31;
    if (node >= N_NODES) return;

    int beg = offsets[node];
    int end = offsets[node + 1];
    const float4* h4 = reinterpret_cast<const float4*>(h);

    float4 acc = make_float4(0, 0, 0, 0);
    for (int i = beg; i < end; ++i) {
        int s = bin_src[i];
        float4 v = h4[(size_t)s * 32 + lane];
        acc.x += v.x; acc.y += v.y; acc.z += v.z; acc.w += v.w;
    }
    float sc = ci[node];
    acc.x *= sc; acc.y *= sc; acc.z *= sc; acc.w *= sc;
    reinterpret_cast<float4*>(out)[(size_t)node * 32 + lane] = acc;
}

// ---------------- Fallback (ws too small): original atomic scatter ----------------
__global__ __launch_bounds__(256) void scatter_kernel(const float* __restrict__ h,
                                                      const float* __restrict__ ci,
                                                      const int* __restrict__ src,
                                                      const int* __restrict__ dst,
                                                      float* __restrict__ out) {
    int gid = blockIdx.x * blockDim.x + threadIdx.x;
    int e = gid >> 5;
    if (e >= N_EDGES) return;
    int lane = gid & 31;
    int s = src[e];
    int d = dst[e];
    float scale = ci[d];
    float4 m = *reinterpret_cast<const float4*>(h + (size_t)s * OUT_F + lane * 4);
    float* o = out + (size_t)d * OUT_F + lane * 4;
    atomicAdd(o + 0, m.x * scale);
    atomicAdd(o + 1, m.y * scale);
    atomicAdd(o + 2, m.z * scale);
    atomicAdd(o + 3, m.w * scale);
}

extern "C" void kernel_launch(void* const* d_in, const int* in_sizes, int n_in,
                              void* d_out, int out_size, void* d_ws, size_t ws_size,
                              hipStream_t stream) {
    const float* feat = (const float*)d_in[0];
    const float* W    = (const float*)d_in[1];
    const float* cj   = (const float*)d_in[2];
    const float* ci   = (const float*)d_in[3];
    const int*   src  = (const int*)d_in[4];
    const int*   dst  = (const int*)d_in[5];
    float* out = (float*)d_out;

    // workspace layout
    const size_t H_BYTES   = (size_t)N_NODES * OUT_F * sizeof(float);   // 51.2 MB
    const size_t OFF_BYTES = ((size_t)(N_NODES + 1) * sizeof(int) + 15) & ~(size_t)15;
    const size_t CUR_BYTES = (size_t)N_NODES * sizeof(int);
    const size_t BIN_BYTES = (size_t)N_EDGES * sizeof(int);

    char* ws = (char*)d_ws;
    float* h      = (float*)ws;                    ws += H_BYTES;
    int* offsets  = (int*)ws;                      ws += OFF_BYTES;
    int* cursor   = (int*)ws;                      ws += CUR_BYTES;
    int* bin_src  = (int*)ws;

    const size_t NEED = H_BYTES + OFF_BYTES + CUR_BYTES + BIN_BYTES;

    gemm_cj_kernel<<<N_NODES / 32, 256, 0, stream>>>(feat, W, cj, h);

    if (ws_size >= NEED) {
        hipMemsetAsync(cursor, 0, CUR_BYTES, stream);
        int eblocks = (N_EDGES + 255) / 256;
        count_kernel<<<eblocks, 256, 0, stream>>>(dst, cursor);
        scan_kernel<<<1, 1024, 0, stream>>>(cursor, offsets);
        fill_kernel<<<eblocks, 256, 0, stream>>>(src, dst, cursor, bin_src);
        gather_kernel<<<(N_NODES + 7) / 8, 256, 0, stream>>>(h, ci, offsets, bin_src, out);
    } else {
        hipMemsetAsync(d_out, 0, (size_t)out_size * sizeof(float), stream);
        int scatter_blocks = (int)(((long long)N_EDGES * 32 + 255) / 256);
        scatter_kernel<<<scatter_blocks, 256, 0, stream>>>(h, ci, src, dst, out);
    }
}

// Round 3
// 627.808 us; speedup vs baseline: 5.0106x; 1.1696x over previous
//
#include <hip/hip_runtime.h>

#define N_NODES 100000
#define N_EDGES 1600000
#define IN_F 256
#define OUT_F 128

// ---------------- LDS-tiled GEMM: h[n][c] = (feat[n,:] @ W[:,c]) * cj[n] -----
// Block = 256 threads -> 128 nodes x 128 cols. KC=32 k-chunk in LDS.
// Thread (tx=tid&15, ty=tid>>4) owns 8x8 outputs at nodes {ty*4+i, 64+ty*4+i},
// cols {tx*4+j, 64+tx*4+j}. Split +64 offsets make ds_read_b128 bank-free.
#define BM 128
#define KC 32
#define FT_PAD 4   // row stride 132 floats: reads conflict-free, writes 4-way worst

__global__ __launch_bounds__(256) void gemm_cj_kernel(const float* __restrict__ feat,
                                                      const float* __restrict__ W,
                                                      const float* __restrict__ cj,
                                                      float* __restrict__ h) {
    __shared__ float ft[KC][BM + FT_PAD];  // [k][node] transposed, 16.9 KB
    __shared__ float wt[KC][OUT_F];        // [k][col], 16 KB

    const int tid = threadIdx.x;
    const int tx = tid & 15;
    const int ty = tid >> 4;
    const int n_base = blockIdx.x * BM;

    const int s_row  = tid >> 3;        // 0..31
    const int s_koff = (tid & 7) * 4;   // 0,4,...,28

    float acc[8][8] = {};

    for (int kc = 0; kc < IN_F; kc += KC) {
        // stage feat transposed: 4 float4 loads -> 16 scalar LDS writes
        #pragma unroll
        for (int i = 0; i < 4; ++i) {
            int row = s_row + i * 32;
            int gn = n_base + row;
            if (gn >= N_NODES) gn = N_NODES - 1;
            float4 v = *reinterpret_cast<const float4*>(feat + (size_t)gn * IN_F + kc + s_koff);
            ft[s_koff + 0][row] = v.x;
            ft[s_koff + 1][row] = v.y;
            ft[s_koff + 2][row] = v.z;
            ft[s_koff + 3][row] = v.w;
        }
        // stage W chunk (contiguous 16 KB): 4 float4 per thread
        const float4* Wc = reinterpret_cast<const float4*>(W + (size_t)kc * OUT_F);
        #pragma unroll
        for (int i = 0; i < 4; ++i) {
            int idx = tid + i * 256;  // float4 index in chunk
            float4 v = Wc[idx];
            *reinterpret_cast<float4*>(&wt[idx >> 5][(idx & 31) * 4]) = v;
        }
        __syncthreads();

        #pragma unroll 8
        for (int k = 0; k < KC; ++k) {
            float4 f0 = *reinterpret_cast<const float4*>(&ft[k][ty * 4]);
            float4 f1 = *reinterpret_cast<const float4*>(&ft[k][64 + ty * 4]);
            float4 w0 = *reinterpret_cast<const float4*>(&wt[k][tx * 4]);
            float4 w1 = *reinterpret_cast<const float4*>(&wt[k][64 + tx * 4]);
            float fv[8] = {f0.x, f0.y, f0.z, f0.w, f1.x, f1.y, f1.z, f1.w};
            float wv[8] = {w0.x, w0.y, w0.z, w0.w, w1.x, w1.y, w1.z, w1.w};
            #pragma unroll
            for (int i = 0; i < 8; ++i)
                #pragma unroll
                for (int j = 0; j < 8; ++j)
                    acc[i][j] = fmaf(fv[i], wv[j], acc[i][j]);
        }
        __syncthreads();
    }

    #pragma unroll
    for (int i = 0; i < 8; ++i) {
        int row = (i < 4) ? (ty * 4 + i) : (64 + ty * 4 + (i - 4));
        int gn = n_base + row;
        if (gn < N_NODES) {
            float s = cj[gn];
            float4 o0 = make_float4(acc[i][0] * s, acc[i][1] * s, acc[i][2] * s, acc[i][3] * s);
            float4 o1 = make_float4(acc[i][4] * s, acc[i][5] * s, acc[i][6] * s, acc[i][7] * s);
            float* hp = h + (size_t)gn * OUT_F;
            *reinterpret_cast<float4*>(hp + tx * 4) = o0;
            *reinterpret_cast<float4*>(hp + 64 + tx * 4) = o1;
        }
    }
}

// ---------------- CSR build ----------------
__global__ __launch_bounds__(256) void count_kernel(const int* __restrict__ dst,
                                                    int* __restrict__ cursor) {
    int e = blockIdx.x * 256 + threadIdx.x;
    if (e < N_EDGES) atomicAdd(&cursor[dst[e]], 1);
}

__global__ __launch_bounds__(1024) void scan_kernel(int* __restrict__ cursor,
                                                    int* __restrict__ offsets) {
    __shared__ int sdata[1024];
    const int t = threadIdx.x;
    const int CHUNK = (N_NODES + 1023) / 1024;
    int lo = t * CHUNK;
    int hi = min(lo + CHUNK, N_NODES);

    int sum = 0;
    for (int i = lo; i < hi; ++i) sum += cursor[i];
    sdata[t] = sum;
    __syncthreads();

    for (int off = 1; off < 1024; off <<= 1) {
        int v = 0;
        if (t >= off) v = sdata[t - off];
        __syncthreads();
        sdata[t] += v;
        __syncthreads();
    }
    int run = sdata[t] - sum;

    for (int i = lo; i < hi; ++i) {
        int c = cursor[i];
        offsets[i] = run;
        cursor[i]  = run;
        run += c;
    }
    if (t == 0) offsets[N_NODES] = N_EDGES;
}

__global__ __launch_bounds__(256) void fill_kernel(const int* __restrict__ src,
                                                   const int* __restrict__ dst,
                                                   int* __restrict__ cursor,
                                                   int* __restrict__ bin_src) {
    int e = blockIdx.x * 256 + threadIdx.x;
    if (e < N_EDGES) {
        int pos = atomicAdd(&cursor[dst[e]], 1);
        bin_src[pos] = src[e];
    }
}

// ---------------- Gather: out[d][c] = ci[d] * sum_{e in bin(d)} h[src_e][c] -----
// 32 lanes per node; 4 source rows in flight to hide random-access latency.
__global__ __launch_bounds__(256) void gather_kernel(const float* __restrict__ h,
                                                     const float* __restrict__ ci,
                                                     const int* __restrict__ offsets,
                                                     const int* __restrict__ bin_src,
                                                     float* __restrict__ out) {
    int node = blockIdx.x * 8 + (threadIdx.x >> 5);
    int lane = threadIdx.x & 31;
    if (node >= N_NODES) return;

    int beg = offsets[node];
    int end = offsets[node + 1];
    const float4* h4 = reinterpret_cast<const float4*>(h);

    float4 acc = make_float4(0, 0, 0, 0);
    int i = beg;
    for (; i + 4 <= end; i += 4) {
        int s0 = bin_src[i + 0];
        int s1 = bin_src[i + 1];
        int s2 = bin_src[i + 2];
        int s3 = bin_src[i + 3];
        float4 v0 = h4[(size_t)s0 * 32 + lane];
        float4 v1 = h4[(size_t)s1 * 32 + lane];
        float4 v2 = h4[(size_t)s2 * 32 + lane];
        float4 v3 = h4[(size_t)s3 * 32 + lane];
        acc.x += (v0.x + v1.x) + (v2.x + v3.x);
        acc.y += (v0.y + v1.y) + (v2.y + v3.y);
        acc.z += (v0.z + v1.z) + (v2.z + v3.z);
        acc.w += (v0.w + v1.w) + (v2.w + v3.w);
    }
    for (; i < end; ++i) {
        int s = bin_src[i];
        float4 v = h4[(size_t)s * 32 + lane];
        acc.x += v.x; acc.y += v.y; acc.z += v.z; acc.w += v.w;
    }
    float sc = ci[node];
    acc.x *= sc; acc.y *= sc; acc.z *= sc; acc.w *= sc;
    reinterpret_cast<float4*>(out)[(size_t)node * 32 + lane] = acc;
}

// ---------------- Fallback (ws too small): atomic scatter ----------------
__global__ __launch_bounds__(256) void scatter_kernel(const float* __restrict__ h,
                                                      const float* __restrict__ ci,
                                                      const int* __restrict__ src,
                                                      const int* __restrict__ dst,
                                                      float* __restrict__ out) {
    int gid = blockIdx.x * blockDim.x + threadIdx.x;
    int e = gid >> 5;
    if (e >= N_EDGES) return;
    int lane = gid & 31;
    int s = src[e];
    int d = dst[e];
    float scale = ci[d];
    float4 m = *reinterpret_cast<const float4*>(h + (size_t)s * OUT_F + lane * 4);
    float* o = out + (size_t)d * OUT_F + lane * 4;
    atomicAdd(o + 0, m.x * scale);
    atomicAdd(o + 1, m.y * scale);
    atomicAdd(o + 2, m.z * scale);
    atomicAdd(o + 3, m.w * scale);
}

extern "C" void kernel_launch(void* const* d_in, const int* in_sizes, int n_in,
                              void* d_out, int out_size, void* d_ws, size_t ws_size,
                              hipStream_t stream) {
    const float* feat = (const float*)d_in[0];
    const float* W    = (const float*)d_in[1];
    const float* cj   = (const float*)d_in[2];
    const float* ci   = (const float*)d_in[3];
    const int*   src  = (const int*)d_in[4];
    const int*   dst  = (const int*)d_in[5];
    float* out = (float*)d_out;

    const size_t H_BYTES   = (size_t)N_NODES * OUT_F * sizeof(float);
    const size_t OFF_BYTES = ((size_t)(N_NODES + 1) * sizeof(int) + 15) & ~(size_t)15;
    const size_t CUR_BYTES = (size_t)N_NODES * sizeof(int);
    const size_t BIN_BYTES = (size_t)N_EDGES * sizeof(int);

    char* ws = (char*)d_ws;
    float* h      = (float*)ws;                    ws += H_BYTES;
    int* offsets  = (int*)ws;                      ws += OFF_BYTES;
    int* cursor   = (int*)ws;                      ws += CUR_BYTES;
    int* bin_src  = (int*)ws;

    const size_t NEED = H_BYTES + OFF_BYTES + CUR_BYTES + BIN_BYTES;

    gemm_cj_kernel<<<(N_NODES + BM - 1) / BM, 256, 0, stream>>>(feat, W, cj, h);

    if (ws_size >= NEED) {
        hipMemsetAsync(cursor, 0, CUR_BYTES, stream);
        int eblocks = (N_EDGES + 255) / 256;
        count_kernel<<<eblocks, 256, 0, stream>>>(dst, cursor);
        scan_kernel<<<1, 1024, 0, stream>>>(cursor, offsets);
        fill_kernel<<<eblocks, 256, 0, stream>>>(src, dst, cursor, bin_src);
        gather_kernel<<<(N_NODES + 7) / 8, 256, 0, stream>>>(h, ci, offsets, bin_src, out);
    } else {
        hipMemsetAsync(d_out, 0, (size_t)out_size * sizeof(float), stream);
        int scatter_blocks = (int)(((long long)N_EDGES * 32 + 255) / 256);
        scatter_kernel<<<scatter_blocks, 256, 0, stream>>>(h, ci, src, dst, out);
    }
}

// Round 4
// 413.061 us; speedup vs baseline: 7.6156x; 1.5199x over previous
//
#include <hip/hip_runtime.h>

#define N_NODES 100000
#define N_EDGES 1600000
#define IN_F 256
#define OUT_F 128

#define N4 (N_NODES / 4)               // 25000 int4 groups (N_NODES % 4 == 0)
#define SCAN_NB ((N4 + 255) / 256)     // 98 blocks

// ---------------- LDS-tiled GEMM: h[n][c] = (feat[n,:] @ W[:,c]) * cj[n] -----
#define BM 128
#define KC 32
#define FT_PAD 4

__global__ __launch_bounds__(256) void gemm_cj_kernel(const float* __restrict__ feat,
                                                      const float* __restrict__ W,
                                                      const float* __restrict__ cj,
                                                      float* __restrict__ h) {
    __shared__ float ft[KC][BM + FT_PAD];
    __shared__ float wt[KC][OUT_F];

    const int tid = threadIdx.x;
    const int tx = tid & 15;
    const int ty = tid >> 4;
    const int n_base = blockIdx.x * BM;

    const int s_row  = tid >> 3;
    const int s_koff = (tid & 7) * 4;

    float acc[8][8] = {};

    for (int kc = 0; kc < IN_F; kc += KC) {
        #pragma unroll
        for (int i = 0; i < 4; ++i) {
            int row = s_row + i * 32;
            int gn = n_base + row;
            if (gn >= N_NODES) gn = N_NODES - 1;
            float4 v = *reinterpret_cast<const float4*>(feat + (size_t)gn * IN_F + kc + s_koff);
            ft[s_koff + 0][row] = v.x;
            ft[s_koff + 1][row] = v.y;
            ft[s_koff + 2][row] = v.z;
            ft[s_koff + 3][row] = v.w;
        }
        const float4* Wc = reinterpret_cast<const float4*>(W + (size_t)kc * OUT_F);
        #pragma unroll
        for (int i = 0; i < 4; ++i) {
            int idx = tid + i * 256;
            float4 v = Wc[idx];
            *reinterpret_cast<float4*>(&wt[idx >> 5][(idx & 31) * 4]) = v;
        }
        __syncthreads();

        #pragma unroll 8
        for (int k = 0; k < KC; ++k) {
            float4 f0 = *reinterpret_cast<const float4*>(&ft[k][ty * 4]);
            float4 f1 = *reinterpret_cast<const float4*>(&ft[k][64 + ty * 4]);
            float4 w0 = *reinterpret_cast<const float4*>(&wt[k][tx * 4]);
            float4 w1 = *reinterpret_cast<const float4*>(&wt[k][64 + tx * 4]);
            float fv[8] = {f0.x, f0.y, f0.z, f0.w, f1.x, f1.y, f1.z, f1.w};
            float wv[8] = {w0.x, w0.y, w0.z, w0.w, w1.x, w1.y, w1.z, w1.w};
            #pragma unroll
            for (int i = 0; i < 8; ++i)
                #pragma unroll
                for (int j = 0; j < 8; ++j)
                    acc[i][j] = fmaf(fv[i], wv[j], acc[i][j]);
        }
        __syncthreads();
    }

    #pragma unroll
    for (int i = 0; i < 8; ++i) {
        int row = (i < 4) ? (ty * 4 + i) : (64 + ty * 4 + (i - 4));
        int gn = n_base + row;
        if (gn < N_NODES) {
            float s = cj[gn];
            float4 o0 = make_float4(acc[i][0] * s, acc[i][1] * s, acc[i][2] * s, acc[i][3] * s);
            float4 o1 = make_float4(acc[i][4] * s, acc[i][5] * s, acc[i][6] * s, acc[i][7] * s);
            float* hp = h + (size_t)gn * OUT_F;
            *reinterpret_cast<float4*>(hp + tx * 4) = o0;
            *reinterpret_cast<float4*>(hp + 64 + tx * 4) = o1;
        }
    }
}

// ---------------- CSR build ----------------
__global__ __launch_bounds__(256) void count_kernel(const int* __restrict__ dst,
                                                    int* __restrict__ cursor) {
    int e = blockIdx.x * 256 + threadIdx.x;
    if (e < N_EDGES) atomicAdd(&cursor[dst[e]], 1);
}

// Multi-block exclusive scan of 100K counts, 3 phases.
__global__ __launch_bounds__(256) void scan_phaseA(const int* __restrict__ counts,
                                                   int* __restrict__ block_sums) {
    __shared__ int sdata[256];
    int t = threadIdx.x;
    int gi4 = blockIdx.x * 256 + t;
    int v = 0;
    if (gi4 < N4) {
        int4 x = reinterpret_cast<const int4*>(counts)[gi4];
        v = (x.x + x.y) + (x.z + x.w);
    }
    sdata[t] = v;
    __syncthreads();
    #pragma unroll
    for (int s = 128; s > 0; s >>= 1) {
        if (t < s) sdata[t] += sdata[t + s];
        __syncthreads();
    }
    if (t == 0) block_sums[blockIdx.x] = sdata[0];
}

__global__ __launch_bounds__(128) void scan_phaseB(int* __restrict__ block_sums) {
    __shared__ int sdata[128];
    int t = threadIdx.x;
    int v = (t < SCAN_NB) ? block_sums[t] : 0;
    sdata[t] = v;
    __syncthreads();
    #pragma unroll
    for (int off = 1; off < 128; off <<= 1) {
        int u = (t >= off) ? sdata[t - off] : 0;
        __syncthreads();
        sdata[t] += u;
        __syncthreads();
    }
    if (t < SCAN_NB) block_sums[t] = sdata[t] - v;   // exclusive block base
}

// Reads counts from `cursor` (in-place safe: each thread rewrites only its own int4),
// writes offsets[] and resets cursor[] to segment starts.
__global__ __launch_bounds__(256) void scan_phaseC(const int* __restrict__ block_sums,
                                                   int* __restrict__ offsets,
                                                   int* __restrict__ cursor) {
    __shared__ int sdata[256];
    int t = threadIdx.x;
    int gi4 = blockIdx.x * 256 + t;
    int4 x = make_int4(0, 0, 0, 0);
    bool valid = gi4 < N4;
    if (valid) x = reinterpret_cast<const int4*>(cursor)[gi4];
    int tot = (x.x + x.y) + (x.z + x.w);
    sdata[t] = tot;
    __syncthreads();
    #pragma unroll
    for (int off = 1; off < 256; off <<= 1) {
        int u = (t >= off) ? sdata[t - off] : 0;
        __syncthreads();
        sdata[t] += u;
        __syncthreads();
    }
    if (valid) {
        int base = block_sums[blockIdx.x] + sdata[t] - tot;
        int4 o;
        o.x = base;
        o.y = base + x.x;
        o.z = o.y + x.y;
        o.w = o.z + x.z;
        reinterpret_cast<int4*>(offsets)[gi4] = o;
        reinterpret_cast<int4*>(cursor)[gi4] = o;
    }
    if (blockIdx.x == 0 && t == 0) offsets[N_NODES] = N_EDGES;
}

__global__ __launch_bounds__(256) void fill_kernel(const int* __restrict__ src,
                                                   const int* __restrict__ dst,
                                                   int* __restrict__ cursor,
                                                   int* __restrict__ bin_src) {
    int e = blockIdx.x * 256 + threadIdx.x;
    if (e < N_EDGES) {
        int pos = atomicAdd(&cursor[dst[e]], 1);
        bin_src[pos] = src[e];
    }
}

// ---------------- Gather: out[d][c] = ci[d] * sum_{e in bin(d)} h[src_e][c] -----
__global__ __launch_bounds__(256) void gather_kernel(const float* __restrict__ h,
                                                     const float* __restrict__ ci,
                                                     const int* __restrict__ offsets,
                                                     const int* __restrict__ bin_src,
                                                     float* __restrict__ out) {
    int node = blockIdx.x * 8 + (threadIdx.x >> 5);
    int lane = threadIdx.x & 31;
    if (node >= N_NODES) return;

    int beg = offsets[node];
    int end = offsets[node + 1];
    const float4* h4 = reinterpret_cast<const float4*>(h);

    float4 acc = make_float4(0, 0, 0, 0);
    int i = beg;
    for (; i + 4 <= end; i += 4) {
        int s0 = bin_src[i + 0];
        int s1 = bin_src[i + 1];
        int s2 = bin_src[i + 2];
        int s3 = bin_src[i + 3];
        float4 v0 = h4[(size_t)s0 * 32 + lane];
        float4 v1 = h4[(size_t)s1 * 32 + lane];
        float4 v2 = h4[(size_t)s2 * 32 + lane];
        float4 v3 = h4[(size_t)s3 * 32 + lane];
        acc.x += (v0.x + v1.x) + (v2.x + v3.x);
        acc.y += (v0.y + v1.y) + (v2.y + v3.y);
        acc.z += (v0.z + v1.z) + (v2.z + v3.z);
        acc.w += (v0.w + v1.w) + (v2.w + v3.w);
    }
    for (; i < end; ++i) {
        int s = bin_src[i];
        float4 v = h4[(size_t)s * 32 + lane];
        acc.x += v.x; acc.y += v.y; acc.z += v.z; acc.w += v.w;
    }
    float sc = ci[node];
    acc.x *= sc; acc.y *= sc; acc.z *= sc; acc.w *= sc;
    reinterpret_cast<float4*>(out)[(size_t)node * 32 + lane] = acc;
}

extern "C" void kernel_launch(void* const* d_in, const int* in_sizes, int n_in,
                              void* d_out, int out_size, void* d_ws, size_t ws_size,
                              hipStream_t stream) {
    const float* feat = (const float*)d_in[0];
    const float* W    = (const float*)d_in[1];
    const float* cj   = (const float*)d_in[2];
    const float* ci   = (const float*)d_in[3];
    const int*   src  = (const int*)d_in[4];
    const int*   dst  = (const int*)d_in[5];
    float* out = (float*)d_out;

    const size_t H_BYTES   = (size_t)N_NODES * OUT_F * sizeof(float);
    const size_t OFF_BYTES = ((size_t)(N_NODES + 1) * sizeof(int) + 15) & ~(size_t)15;
    const size_t CUR_BYTES = (size_t)N_NODES * sizeof(int);
    const size_t BS_BYTES  = ((size_t)SCAN_NB * sizeof(int) + 15) & ~(size_t)15;
    const size_t BIN_BYTES = (size_t)N_EDGES * sizeof(int);

    char* ws = (char*)d_ws;
    float* h        = (float*)ws;   ws += H_BYTES;
    int* offsets    = (int*)ws;     ws += OFF_BYTES;
    int* cursor     = (int*)ws;     ws += CUR_BYTES;
    int* block_sums = (int*)ws;     ws += BS_BYTES;
    int* bin_src    = (int*)ws;

    gemm_cj_kernel<<<(N_NODES + BM - 1) / BM, 256, 0, stream>>>(feat, W, cj, h);

    hipMemsetAsync(cursor, 0, CUR_BYTES, stream);
    int eblocks = (N_EDGES + 255) / 256;
    count_kernel<<<eblocks, 256, 0, stream>>>(dst, cursor);
    scan_phaseA<<<SCAN_NB, 256, 0, stream>>>(cursor, block_sums);
    scan_phaseB<<<1, 128, 0, stream>>>(block_sums);
    scan_phaseC<<<SCAN_NB, 256, 0, stream>>>(block_sums, offsets, cursor);
    fill_kernel<<<eblocks, 256, 0, stream>>>(src, dst, cursor, bin_src);
    gather_kernel<<<(N_NODES + 7) / 8, 256, 0, stream>>>(h, ci, offsets, bin_src, out);
}